// Round 12
// baseline (5110.347 us; speedup 1.0000x reference)
//
#include <hip/hip_runtime.h>

#define NB 256      // batch
#define NT 512      // time steps
#define NH 1024     // hidden
#define BH (NB * NH)
#define GRID_WGS 256
#define BLOCK 512
#define T2 (2 * NT)

typedef __attribute__((ext_vector_type(8))) __bf16 bfrag;
typedef __attribute__((ext_vector_type(4))) float f32x4;
typedef __attribute__((ext_vector_type(4))) unsigned u32x4;
typedef __attribute__((ext_vector_type(2))) unsigned u32x2;
typedef __attribute__((ext_vector_type(8))) unsigned short u16x8;
typedef unsigned short us;

// h1(t) in buf[t&3]; h2(t) in buf[t&3] (quad buffers; skew bounded by gates)
__device__ __attribute__((aligned(16))) us g_h1[4 * BH];
__device__ __attribute__((aligned(16))) us g_h2[4 * BH];
// monotonic flags; BOTH arrays advance exactly NT+1 per launch (replay-safe)
__device__ __attribute__((aligned(128))) unsigned g_flagA[128];
__device__ __attribute__((aligned(128))) unsigned g_flagB[128];

__device__ __forceinline__ us f2bf(float f) {
  union { float f; unsigned u; } v; v.f = f;
  unsigned r = v.u + 0x7FFFu + ((v.u >> 16) & 1u);  // RTE
  return (us)(r >> 16);
}
__device__ __forceinline__ float bf2f(us u) {
  union { unsigned u; float f; } v; v.u = ((unsigned)u) << 16;
  return v.f;
}
__device__ __forceinline__ bfrag cvt8(const float* __restrict__ p) {
  f32x4 a = *reinterpret_cast<const f32x4*>(p);
  f32x4 b = *reinterpret_cast<const f32x4*>(p + 4);
  u16x8 u;
#pragma unroll
  for (int i = 0; i < 4; ++i) { u[i] = f2bf(a[i]); u[i + 4] = f2bf(b[i]); }
  union { u16x8 u; bfrag b; } c; c.u = u; return c.b;
}

// ---- device-coherent (sc0 sc1 -> L3 coherence point) ops
union f16u { u32x4 v; bfrag b; u16x8 s; };
__device__ __forceinline__ u32x4 ld16_dev(const void* p) {
  u32x4 r;
  asm volatile("global_load_dwordx4 %0, %1, off sc0 sc1" : "=v"(r) : "v"(p));
  return r;   // caller must s_waitcnt before use
}
__device__ __forceinline__ unsigned ld4_dev(const void* p) {
  unsigned r;
  asm volatile("global_load_dword %0, %1, off sc0 sc1\n\ts_waitcnt vmcnt(0)"
               : "=v"(r) : "v"(p) : "memory");
  return r;
}
__device__ __forceinline__ void st4_dev(void* p, unsigned v) {
  asm volatile("global_store_dword %0, %1, off sc0 sc1" :: "v"(p), "v"(v) : "memory");
}
__device__ __forceinline__ void st8_dev(void* p, unsigned lo, unsigned hi) {
  u32x2 v = {lo, hi};
  asm volatile("global_store_dwordx2 %0, %1, off sc0 sc1" :: "v"(p), "v"(v) : "memory");
}

// per-lane poll: lanes with p==null idle
__device__ __forceinline__ void poll(const unsigned* p, unsigned t) {
  if (!p) t = 0u;
  unsigned v = 0u;
  for (;;) {
    if (p) v = ld4_dev(p);
    if (!__any((int)(v < t))) break;
    __builtin_amdgcn_s_sleep(1);
  }
}

__device__ __forceinline__ unsigned cadd(unsigned* c) {
  return __hip_atomic_fetch_add(c, 1u, __ATOMIC_RELAXED, __HIP_MEMORY_SCOPE_WORKGROUP);
}

#define MFMA(a, b, c) __builtin_amdgcn_mfma_f32_16x16x32_bf16((a), (b), (c), 0, 0, 0)
#define SB() __builtin_amdgcn_sched_barrier(0)
#define VM0() do { asm volatile("s_waitcnt vmcnt(0)" ::: "memory"); SB(); } while (0)

__global__ void __launch_bounds__(BLOCK, 1) rnn_kernel(
    const float* __restrict__ x,     // [B][2][T]
    const float* __restrict__ Wi1,   // [H][2]
    const float* __restrict__ Whh1,  // [H][H]
    const float* __restrict__ Wih2,  // [H][H]
    const float* __restrict__ Whh2,  // [H][H]
    const float* __restrict__ bih1,
    const float* __restrict__ bhh1,
    const float* __restrict__ bih2,
    const float* __restrict__ bhh2,
    const float* __restrict__ Wlin,  // [2][H]
    const float* __restrict__ blin,  // [2]
    float* __restrict__ out)         // [B][2][T]
{
  const int bid = blockIdx.x, tid = threadIdx.x;
  const int w = tid >> 6, lane = tid & 63;
  const int isB = bid >> 7;                 // 0..127: layer-1 (A), 128..255: layer-2 (B)
  const int g = (bid >> 4) & 7, s = bid & 15;  // group rows [g*32,+32); slot cols [s*64,+64)
  unsigned* fA = g_flagA + g * 16;
  unsigned* fB = g_flagB + g * 16;
  unsigned* fown = (isB ? fB : fA) + s;
  const unsigned fb = ld4_dev(fown);        // own flag -> stable base (bases equal across arrays)

  __shared__ unsigned s_cnt;
  __shared__ float red[8][32][68];
  if (tid == 0) s_cnt = 0;

  // zero t=-1 tile: A -> h1 buf3; B -> h2 buf3 (32 rows x 64 cols)
  {
    const int zr = tid >> 4;
    unsigned* base = (unsigned*)((isB ? g_h2 : g_h1) + 3 * BH)
                   + ((g * 32 + zr) * NH + s * 64) / 2 + (tid & 15) * 2;
    st8_dev(base, 0u, 0u);
  }

  const int fr = lane & 15;
  const int ko = (lane >> 4) << 3;          // 0,8,16,24
  const int prow = (lane >> 4) << 2;        // C/D row base in 16x16
  const int kbase = w * 128;                // wave K-slice [w*128,+128) = slots {2w,2w+1}
  const int arow = g * 32 + fr;             // A-frag row base (+16 for mf1)
  const int erow = tid >> 4, ecol = (tid & 15) * 4;
  const int growE = g * 32 + erow, gcolE = s * 64 + ecol;

  // ---- persistent weights
  bfrag wgt1[4][4], wgt2[4][4];   // A: wgt1=W_hh1 (wgt2 unused). B: wgt1=W_ih2, wgt2=W_hh2.
#pragma unroll
  for (int cf = 0; cf < 4; ++cf)
#pragma unroll
    for (int st = 0; st < 4; ++st) {
      const int off = (s * 64 + cf * 16 + fr) * NH + kbase + st * 32 + ko;
      if (!isB) {
        wgt1[cf][st] = cvt8(Whh1 + off);
      } else {
        wgt1[cf][st] = cvt8(Wih2 + off);
        wgt2[cf][st] = cvt8(Whh2 + off);
      }
    }

  // ---- epilogue constants
  f32x4 bsum, wi0 = {}, wi1 = {};
  if (!isB) {
    bsum = *reinterpret_cast<const f32x4*>(bih1 + gcolE)
         + *reinterpret_cast<const f32x4*>(bhh1 + gcolE);
#pragma unroll
    for (int j = 0; j < 4; ++j) {
      wi0[j] = Wi1[(gcolE + j) * 2];
      wi1[j] = Wi1[(gcolE + j) * 2 + 1];
    }
  } else {
    bsum = *reinterpret_cast<const f32x4*>(bih2 + gcolE)
         + *reinterpret_cast<const f32x4*>(bhh2 + gcolE);
  }
  const float* xrow = x + growE * T2;

  // out duty (A-WGs, waves 0..3): row r_out, col c
  const int r_out = g * 32 + 2 * s + (w >> 1), c = w & 1;
  float wl[16];
  if (!isB && w < 4) {
#pragma unroll
    for (int j = 0; j < 16; ++j) wl[j] = Wlin[c * NH + lane * 16 + j];
  }

  // preamble done -> publish fb+1 ("state(-1) ready")
  VM0();
  __syncthreads();
  if (tid == 0) st4_dev(fown, fb + 1u);

  if (!isB) {
    // ========== A: h1(q) = tanh(h1(q-1)W1^T + x_q Wi1^T + b1), q = 0..NT-1
    for (int q = 0; q < NT; ++q) {
      const us* h1p = g_h1 + ((q + 3) & 3) * BH;
      us*       h1c = g_h1 + (q & 3) * BH;
      const us* h2o = g_h2 + (q & 3) * BH;          // h2(q-4) (q-4 == q mod 4)
      const float x0 = xrow[q], x1 = xrow[NT + q];

      // wait: my 2 K-producers done h1(q-1); all 16 fB done h2(q-4) [buffer+out gate]
      {
        const unsigned* pp = nullptr; unsigned tt = 0u;
        if (lane < 2)                         { pp = fA + 2 * w + lane; tt = fb + 1u + (unsigned)q; }
        else if (lane >= 32 && lane < 48 && q >= 3) { pp = fB + (lane - 32); tt = fb + (unsigned)q - 2u; }
        poll(pp, tt);
      }
      SB();

      f16u a[2][4], o0, o1;
      {
        const us* pa0 = h1p + arow * NH + kbase + ko;
        const us* pa1 = h1p + (arow + 16) * NH + kbase + ko;
#pragma unroll
        for (int st = 0; st < 4; ++st) a[0][st].v = ld16_dev(pa0 + st * 32);
#pragma unroll
        for (int st = 0; st < 4; ++st) a[1][st].v = ld16_dev(pa1 + st * 32);
        if (w < 4 && q >= 4) {                      // out(q-4) rows, gated above
          o0.v = ld16_dev(h2o + r_out * NH + lane * 16);
          o1.v = ld16_dev(h2o + r_out * NH + lane * 16 + 8);
        }
      }
      VM0();

      f32x4 acc[2][4] = {};
#pragma unroll
      for (int st = 0; st < 4; ++st)
#pragma unroll
        for (int cf = 0; cf < 4; ++cf) {
          acc[0][cf] = MFMA(a[0][st].b, wgt1[cf][st], acc[0][cf]);
          acc[1][cf] = MFMA(a[1][st].b, wgt1[cf][st], acc[1][cf]);
        }
#pragma unroll
      for (int mf = 0; mf < 2; ++mf)
#pragma unroll
        for (int cf = 0; cf < 4; ++cf)
#pragma unroll
          for (int r = 0; r < 4; ++r)
            red[w][mf * 16 + prow + r][cf * 16 + fr] = acc[mf][cf][r];
      __syncthreads();

      f32x4 sv = {};
#pragma unroll
      for (int u = 0; u < 8; ++u)
        sv += *reinterpret_cast<const f32x4*>(&red[u][erow][ecol]);
      const f32x4 v = sv + bsum + x0 * wi0 + x1 * wi1;
      st8_dev(h1c + growE * NH + gcolE,
              (unsigned)f2bf(tanhf(v[0])) | ((unsigned)f2bf(tanhf(v[1])) << 16),
              (unsigned)f2bf(tanhf(v[2])) | ((unsigned)f2bf(tanhf(v[3])) << 16));
      VM0();
      if (lane == 0) {
        const unsigned old = cadd(&s_cnt);
        if (old == 8u * (unsigned)q + 7u) st4_dev(fA + s, fb + 2u + (unsigned)q);
      }

      if (w < 4 && q >= 4) {                        // out(q-4): regs already loaded
        float so = 0.f;
#pragma unroll
        for (int e = 0; e < 8; ++e) {
          so = fmaf(bf2f(o0.s[e]), wl[e],     so);
          so = fmaf(bf2f(o1.s[e]), wl[8 + e], so);
        }
#pragma unroll
        for (int m = 1; m < 64; m <<= 1) so += __shfl_xor(so, m);
        if (lane == 0) out[r_out * T2 + c * NT + (q - 4)] = so + blin[c];
      }
    }

    // tail: out(NT-4 .. NT-1) after B fully done
    {
      const unsigned* pp = (lane < 16) ? fB + lane : nullptr;
      poll(pp, fb + 1u + (unsigned)NT);
    }
    if (w < 4) {
      for (int t = NT - 4; t < NT; ++t) {
        const us* h2t = g_h2 + (t & 3) * BH;
        f16u o0, o1;
        o0.v = ld16_dev(h2t + r_out * NH + lane * 16);
        o1.v = ld16_dev(h2t + r_out * NH + lane * 16 + 8);
        VM0();
        float so = 0.f;
#pragma unroll
        for (int e = 0; e < 8; ++e) {
          so = fmaf(bf2f(o0.s[e]), wl[e],     so);
          so = fmaf(bf2f(o1.s[e]), wl[8 + e], so);
        }
#pragma unroll
        for (int m = 1; m < 64; m <<= 1) so += __shfl_xor(so, m);
        if (lane == 0) out[r_out * T2 + c * NT + t] = so + blin[c];
      }
    }

  } else {
    // ========== B: h2(p-1) = tanh(h1(p-1)W2i^T + h2(p-2)W2h^T + b2), p = 1..NT
    for (int p = 1; p <= NT; ++p) {
      const us* h1p = g_h1 + ((p + 3) & 3) * BH;    // h1(p-1)
      const us* h2p = g_h2 + ((p + 2) & 3) * BH;    // h2(p-2)
      us*       h2c = g_h2 + ((p + 3) & 3) * BH;    // h2(p-1)

      // wait: h1(p-1) from my 2 A-producers; h2(p-2) from my 2 B-producers
      {
        const unsigned* pp = nullptr; unsigned tt = 0u;
        if (lane < 2)      { pp = fA + 2 * w + lane;       tt = fb + (unsigned)p + 1u; }
        else if (lane < 4) { pp = fB + 2 * w + (lane - 2); tt = fb + (unsigned)p; }
        poll(pp, tt);
      }
      SB();

      f16u a1[2][4], a2[2][4];
      {
        const us* p10 = h1p + arow * NH + kbase + ko;
        const us* p11 = h1p + (arow + 16) * NH + kbase + ko;
        const us* p20 = h2p + arow * NH + kbase + ko;
        const us* p21 = h2p + (arow + 16) * NH + kbase + ko;
#pragma unroll
        for (int st = 0; st < 4; ++st) a1[0][st].v = ld16_dev(p10 + st * 32);
#pragma unroll
        for (int st = 0; st < 4; ++st) a1[1][st].v = ld16_dev(p11 + st * 32);
#pragma unroll
        for (int st = 0; st < 4; ++st) a2[0][st].v = ld16_dev(p20 + st * 32);
#pragma unroll
        for (int st = 0; st < 4; ++st) a2[1][st].v = ld16_dev(p21 + st * 32);
      }
      VM0();

      f32x4 acc[2][4] = {};
#pragma unroll
      for (int st = 0; st < 4; ++st)
#pragma unroll
        for (int cf = 0; cf < 4; ++cf) {
          acc[0][cf] = MFMA(a1[0][st].b, wgt1[cf][st], acc[0][cf]);
          acc[0][cf] = MFMA(a2[0][st].b, wgt2[cf][st], acc[0][cf]);
          acc[1][cf] = MFMA(a1[1][st].b, wgt1[cf][st], acc[1][cf]);
          acc[1][cf] = MFMA(a2[1][st].b, wgt2[cf][st], acc[1][cf]);
        }
#pragma unroll
      for (int mf = 0; mf < 2; ++mf)
#pragma unroll
        for (int cf = 0; cf < 4; ++cf)
#pragma unroll
          for (int r = 0; r < 4; ++r)
            red[w][mf * 16 + prow + r][cf * 16 + fr] = acc[mf][cf][r];
      __syncthreads();

      f32x4 sv = {};
#pragma unroll
      for (int u = 0; u < 8; ++u)
        sv += *reinterpret_cast<const f32x4*>(&red[u][erow][ecol]);
      const f32x4 v = sv + bsum;
      st8_dev(h2c + growE * NH + gcolE,
              (unsigned)f2bf(tanhf(v[0])) | ((unsigned)f2bf(tanhf(v[1])) << 16),
              (unsigned)f2bf(tanhf(v[2])) | ((unsigned)f2bf(tanhf(v[3])) << 16));
      VM0();
      if (lane == 0) {
        const unsigned old = cadd(&s_cnt);
        if (old == 8u * (unsigned)(p - 1) + 7u) st4_dev(fB + s, fb + 1u + (unsigned)p);
      }
    }
  }
}

extern "C" void kernel_launch(void* const* d_in, const int* in_sizes, int n_in,
                              void* d_out, int out_size, void* d_ws, size_t ws_size,
                              hipStream_t stream) {
  (void)in_sizes; (void)n_in; (void)d_ws; (void)ws_size; (void)out_size;
  const float* x    = (const float*)d_in[0];
  const float* Wi1  = (const float*)d_in[1];
  const float* Whh1 = (const float*)d_in[2];
  const float* bih1 = (const float*)d_in[3];
  const float* bhh1 = (const float*)d_in[4];
  const float* Wih2 = (const float*)d_in[5];
  const float* Whh2 = (const float*)d_in[6];
  const float* bih2 = (const float*)d_in[7];
  const float* bhh2 = (const float*)d_in[8];
  const float* Wlin = (const float*)d_in[9];
  const float* blin = (const float*)d_in[10];
  float* out = (float*)d_out;

  void* args[] = { (void*)&x, (void*)&Wi1, (void*)&Whh1, (void*)&Wih2, (void*)&Whh2,
                   (void*)&bih1, (void*)&bhh1, (void*)&bih2, (void*)&bhh2,
                   (void*)&Wlin, (void*)&blin, (void*)&out };
  hipLaunchCooperativeKernel((void*)rnn_kernel, dim3(GRID_WGS), dim3(BLOCK),
                             args, 0, stream);
}

// Round 13
// 3977.318 us; speedup vs baseline: 1.2849x; 1.2849x over previous
//
#include <hip/hip_runtime.h>

#define NB 256      // batch
#define NT 512      // time steps
#define NH 1024     // hidden
#define BH (NB * NH)
#define GRID_WGS 256
#define BLOCK 512
#define T2 (2 * NT)

typedef __attribute__((ext_vector_type(8))) __bf16 bfrag;
typedef __attribute__((ext_vector_type(4))) float f32x4;
typedef __attribute__((ext_vector_type(4))) unsigned u32x4;
typedef __attribute__((ext_vector_type(8))) unsigned short u16x8;
typedef unsigned short us;

// h1(t) in buf[t&3]; h2(t) in buf[t&3] (quad buffers: skew-proof)
__device__ __attribute__((aligned(16))) us g_h1[4 * BH];
__device__ __attribute__((aligned(16))) us g_h2[4 * BH];
// per-(group,slot) monotonic flags, +NT+2 per launch (never reset -> replay safe)
__device__ __attribute__((aligned(128))) unsigned g_flag[GRID_WGS];

__device__ __forceinline__ us f2bf(float f) {
  union { float f; unsigned u; } v; v.f = f;
  unsigned r = v.u + 0x7FFFu + ((v.u >> 16) & 1u);  // RTE
  return (us)(r >> 16);
}
__device__ __forceinline__ float bf2f(us u) {
  union { unsigned u; float f; } v; v.u = ((unsigned)u) << 16;
  return v.f;
}
__device__ __forceinline__ bfrag cvt8(const float* __restrict__ p) {
  f32x4 a = *reinterpret_cast<const f32x4*>(p);
  f32x4 b = *reinterpret_cast<const f32x4*>(p + 4);
  u16x8 u;
#pragma unroll
  for (int i = 0; i < 4; ++i) { u[i] = f2bf(a[i]); u[i + 4] = f2bf(b[i]); }
  union { u16x8 u; bfrag b; } c; c.u = u; return c.b;
}

// ---- device-coherent (sc0 sc1 -> L3 coherence point) ops
union f16u { u32x4 v; bfrag b; u16x8 s; };
__device__ __forceinline__ u32x4 ld16_dev(const void* p) {
  u32x4 r;
  asm volatile("global_load_dwordx4 %0, %1, off sc0 sc1" : "=v"(r) : "v"(p));
  return r;   // caller must s_waitcnt before use
}
__device__ __forceinline__ unsigned ld4_dev(const void* p) {
  unsigned r;
  asm volatile("global_load_dword %0, %1, off sc0 sc1\n\ts_waitcnt vmcnt(0)"
               : "=v"(r) : "v"(p) : "memory");
  return r;
}
__device__ __forceinline__ void st4_dev(void* p, unsigned v) {
  asm volatile("global_store_dword %0, %1, off sc0 sc1" :: "v"(p), "v"(v) : "memory");
}

// poll 4 flags with lanes 0..3 only
__device__ __forceinline__ void wait4(const unsigned* f, int lane, unsigned tgt) {
  unsigned v = tgt;
  for (;;) {
    if (lane < 4) v = ld4_dev(f + lane);
    if (!__any((int)(v < tgt))) break;
    __builtin_amdgcn_s_sleep(1);
  }
}
__device__ __forceinline__ void wait32(const unsigned* f, int lane, unsigned tgt) {
  unsigned v = tgt;
  for (;;) {
    if (lane < 32) v = ld4_dev(f + lane);
    if (!__any((int)(v < tgt))) break;
    __builtin_amdgcn_s_sleep(1);
  }
}

__device__ __forceinline__ unsigned cadd(unsigned* c) {
  return __hip_atomic_fetch_add(c, 1u, __ATOMIC_RELAXED, __HIP_MEMORY_SCOPE_WORKGROUP);
}

#define MFMA(a, b, c) __builtin_amdgcn_mfma_f32_16x16x32_bf16((a), (b), (c), 0, 0, 0)
#define SB() __builtin_amdgcn_sched_barrier(0)

__global__ void __launch_bounds__(BLOCK, 1) rnn_kernel(
    const float* __restrict__ x,     // [B][2][T]
    const float* __restrict__ Wi1,   // [H][2]
    const float* __restrict__ Whh1,  // [H][H]
    const float* __restrict__ Wih2,  // [H][H]
    const float* __restrict__ Whh2,  // [H][H]
    const float* __restrict__ bih1,
    const float* __restrict__ bhh1,
    const float* __restrict__ bih2,
    const float* __restrict__ bhh2,
    const float* __restrict__ Wlin,  // [2][H]
    const float* __restrict__ blin,  // [2]
    float* __restrict__ out)         // [B][2][T]
{
  const int bid = blockIdx.x, tid = threadIdx.x;
  const int w = tid >> 6, lane = tid & 63;
  const int mb = bid >> 5, nb = bid & 31;  // group rows [mb*32,+32); slot cols [nb*32,+32)
  unsigned* gf = g_flag + mb * 32;
  const unsigned fb = ld4_dev(&gf[nb]);    // own flag -> stable base

  __shared__ float redA[2][8][32][36];
  __shared__ float redB[2][8][32][36];
  __shared__ unsigned s_cnt;
  if (tid == 0) s_cnt = 0;

  // zero t<0 tiles: h1(-1)=h1 buf3; h2(-2)=h2 buf2; h2(-1)=h2 buf3
  {
    const int zrow = tid >> 4, zc = tid & 15;
    const int off_d = ((mb * 32 + zrow) * NH + nb * 32) / 2 + zc;
    st4_dev((unsigned*)(g_h1 + 3 * BH) + off_d, 0u);
    st4_dev((unsigned*)(g_h2 + 2 * BH) + off_d, 0u);
    st4_dev((unsigned*)(g_h2 + 3 * BH) + off_d, 0u);
  }

  // ---- persistent weights: wave w owns K-slice [w*128,+128), 32 cols
  const int fr = lane & 15;
  const int ko = (lane >> 4) << 3;
  const int kbase = w * 128;
  bfrag w1[2][4], w2i[2][4], w2h[2][4];    // [col-half cf][k-step st]
#pragma unroll
  for (int cf = 0; cf < 2; ++cf)
#pragma unroll
    for (int st = 0; st < 4; ++st) {
      const int off = (nb * 32 + cf * 16 + fr) * NH + kbase + st * 32 + ko;
      w1[cf][st]  = cvt8(Whh1 + off);
      w2i[cf][st] = cvt8(Wih2 + off);
      w2h[cf][st] = cvt8(Whh2 + off);
    }

  // ---- per-thread epilogue constants (2 adjacent cols of one row)
  const int rl = tid >> 4, cl = (tid & 15) * 2;
  const int grow = mb * 32 + rl, gcol = nb * 32 + cl;
  const float b1s0 = bih1[gcol] + bhh1[gcol];
  const float b1s1 = bih1[gcol + 1] + bhh1[gcol + 1];
  const float b2s0 = bih2[gcol] + bhh2[gcol];
  const float b2s1 = bih2[gcol + 1] + bhh2[gcol + 1];
  const float wi00 = Wi1[gcol * 2],       wi01 = Wi1[gcol * 2 + 1];
  const float wi10 = Wi1[(gcol + 1) * 2], wi11 = Wi1[(gcol + 1) * 2 + 1];
  const float* xrow = x + grow * T2;

  const int arow0 = mb * 32 + fr;     // A-frag row base (+16 for mf1)
  const int prow = (lane >> 4) << 2;  // C/D row base within 16x16 frag
  const int r_g = bid;                // this WG's out row (mb*32+nb)

  float wl[16]; float blc = 0.f;      // Wlin row (waves 0,1 only)
  if (w < 2) {
#pragma unroll
    for (int j = 0; j < 16; ++j) wl[j] = Wlin[w * NH + lane * 16 + j];
    blc = blin[w];
  }

  // preamble complete -> publish fb+1
  asm volatile("s_waitcnt vmcnt(0)" ::: "memory");
  __syncthreads();
  if (tid == 0) st4_dev(&gf[nb], fb + 1u);

  for (int p = 0; p <= NT; ++p) {
    const int par = p & 1;
    const us* h1_prev = g_h1 + ((p + 3) & 3) * BH;   // h1(p-1)
    us*       h1_cur  = g_h1 + (p & 3) * BH;         // h1(p)
    const us* h2_pp   = g_h2 + ((p + 2) & 3) * BH;   // h2(p-2)
    us*       h2_cur  = g_h2 + ((p + 3) & 3) * BH;   // h2(p-1)
    const us* h2_out  = g_h2 + ((p + 1) & 3) * BH;   // h2(p-3)

    // x prefetch (plain cached loads; drained by poll's vmcnt(0))
    const int px = (p < NT) ? p : 0;
    const float x0 = xrow[px], x1 = xrow[NT + px];

    // wave w waits only on its 4 K-producer slots (all >= end of phase p-1)
    wait4(gf + w * 4, lane, fb + 1u + (unsigned)p);
    SB();

    // load burst: out rows FIRST (uniform vmcnt counting), then a1 (8), a2 (8)
    f16u o0, o1, a1[2][4], a2[2][4];
    const int do_out = (w < 2) && (p >= 3);
    if (do_out) {
      o0.v = ld16_dev(h2_out + r_g * NH + lane * 16);
      o1.v = ld16_dev(h2_out + r_g * NH + lane * 16 + 8);
    }
    {
      const us* pa0 = h1_prev + arow0 * NH + kbase + ko;
      const us* pa1 = h1_prev + (arow0 + 16) * NH + kbase + ko;
#pragma unroll
      for (int st = 0; st < 4; ++st) a1[0][st].v = ld16_dev(pa0 + st * 32);
#pragma unroll
      for (int st = 0; st < 4; ++st) a1[1][st].v = ld16_dev(pa1 + st * 32);
      const us* pb0 = h2_pp + arow0 * NH + kbase + ko;
      const us* pb1 = h2_pp + (arow0 + 16) * NH + kbase + ko;
#pragma unroll
      for (int st = 0; st < 4; ++st) a2[0][st].v = ld16_dev(pb0 + st * 32);
#pragma unroll
      for (int st = 0; st < 4; ++st) a2[1][st].v = ld16_dev(pb1 + st * 32);
    }

    f32x4 accA[2][2] = {}; f32x4 accB[2][2] = {};
    asm volatile("s_waitcnt vmcnt(8)" ::: "memory");   // o + a1 done
    SB();
#pragma unroll
    for (int st = 0; st < 4; ++st) {
      accA[0][0] = MFMA(a1[0][st].b, w1[0][st],  accA[0][0]);
      accA[0][1] = MFMA(a1[0][st].b, w1[1][st],  accA[0][1]);
      accA[1][0] = MFMA(a1[1][st].b, w1[0][st],  accA[1][0]);
      accA[1][1] = MFMA(a1[1][st].b, w1[1][st],  accA[1][1]);
      accB[0][0] = MFMA(a1[0][st].b, w2i[0][st], accB[0][0]);
      accB[0][1] = MFMA(a1[0][st].b, w2i[1][st], accB[0][1]);
      accB[1][0] = MFMA(a1[1][st].b, w2i[0][st], accB[1][0]);
      accB[1][1] = MFMA(a1[1][st].b, w2i[1][st], accB[1][1]);
    }
    asm volatile("s_waitcnt vmcnt(0)" ::: "memory");   // a2 done
    SB();
#pragma unroll
    for (int st = 0; st < 4; ++st) {
      accB[0][0] = MFMA(a2[0][st].b, w2h[0][st], accB[0][0]);
      accB[0][1] = MFMA(a2[0][st].b, w2h[1][st], accB[0][1]);
      accB[1][0] = MFMA(a2[1][st].b, w2h[0][st], accB[1][0]);
      accB[1][1] = MFMA(a2[1][st].b, w2h[1][st], accB[1][1]);
    }

    // k-partials to parity-buffered LDS  (C/D: col = lane&15, row = (lane>>4)*4+r)
#pragma unroll
    for (int mf = 0; mf < 2; ++mf)
#pragma unroll
      for (int cf = 0; cf < 2; ++cf)
#pragma unroll
        for (int r = 0; r < 4; ++r) {
          redA[par][w][mf * 16 + prow + r][cf * 16 + fr] = accA[mf][cf][r];
          redB[par][w][mf * 16 + prow + r][cf * 16 + fr] = accB[mf][cf][r];
        }
    __syncthreads();   // single barrier per phase (red is parity-double-buffered)

    // 8-way k-reduction + fused epilogue
    float sA0 = 0.f, sA1 = 0.f, sB0 = 0.f, sB1 = 0.f;
#pragma unroll
    for (int u = 0; u < 8; ++u) {
      const float2 a = *reinterpret_cast<const float2*>(&redA[par][u][rl][cl]);
      const float2 b = *reinterpret_cast<const float2*>(&redB[par][u][rl][cl]);
      sA0 += a.x; sA1 += a.y; sB0 += b.x; sB1 += b.y;
    }
    if (p < NT) {
      const float v0 = sA0 + b1s0 + x0 * wi00 + x1 * wi01;
      const float v1 = sA1 + b1s1 + x0 * wi10 + x1 * wi11;
      st4_dev(h1_cur + grow * NH + gcol,
              (unsigned)f2bf(tanhf(v0)) | ((unsigned)f2bf(tanhf(v1)) << 16));
    }
    if (p >= 1) {
      const float v0 = sB0 + b2s0;
      const float v1 = sB1 + b2s1;
      st4_dev(h2_cur + grow * NH + gcol,
              (unsigned)f2bf(tanhf(v0)) | ((unsigned)f2bf(tanhf(v1)) << 16));
    }

    // per-wave ack + counter publish (no second barrier)
    asm volatile("s_waitcnt vmcnt(0)" ::: "memory");
    if (lane == 0) {
      const unsigned old = cadd(&s_cnt);
      if (old == 8u * (unsigned)p + 7u) st4_dev(&gf[nb], fb + 2u + (unsigned)p);
    }

    // out(p-3): registers already loaded in the burst; off critical path
    if (do_out) {
      float so = 0.f;
#pragma unroll
      for (int e = 0; e < 8; ++e) {
        so = fmaf(bf2f(o0.s[e]), wl[e],     so);
        so = fmaf(bf2f(o1.s[e]), wl[8 + e], so);
      }
#pragma unroll
      for (int m = 1; m < 64; m <<= 1) so += __shfl_xor(so, m);
      if (lane == 0) out[r_g * T2 + w * NT + (p - 3)] = so + blc;
    }
  }

  // tail: out(NT-2), out(NT-1) need all slots through phase NT
  wait32(gf, lane, fb + 2u + (unsigned)NT);
  if (w < 2) {
#pragma unroll
    for (int t = NT - 2; t < NT; ++t) {
      const us* h2t = g_h2 + (t & 3) * BH;
      f16u o0, o1;
      o0.v = ld16_dev(h2t + r_g * NH + lane * 16);
      o1.v = ld16_dev(h2t + r_g * NH + lane * 16 + 8);
      asm volatile("s_waitcnt vmcnt(0)" ::: "memory");
      SB();
      float so = 0.f;
#pragma unroll
      for (int e = 0; e < 8; ++e) {
        so = fmaf(bf2f(o0.s[e]), wl[e],     so);
        so = fmaf(bf2f(o1.s[e]), wl[8 + e], so);
      }
#pragma unroll
      for (int m = 1; m < 64; m <<= 1) so += __shfl_xor(so, m);
      if (lane == 0) out[r_g * T2 + w * NT + t] = so + blc;
    }
  }
}

extern "C" void kernel_launch(void* const* d_in, const int* in_sizes, int n_in,
                              void* d_out, int out_size, void* d_ws, size_t ws_size,
                              hipStream_t stream) {
  (void)in_sizes; (void)n_in; (void)d_ws; (void)ws_size; (void)out_size;
  const float* x    = (const float*)d_in[0];
  const float* Wi1  = (const float*)d_in[1];
  const float* Whh1 = (const float*)d_in[2];
  const float* bih1 = (const float*)d_in[3];
  const float* bhh1 = (const float*)d_in[4];
  const float* Wih2 = (const float*)d_in[5];
  const float* Whh2 = (const float*)d_in[6];
  const float* bih2 = (const float*)d_in[7];
  const float* bhh2 = (const float*)d_in[8];
  const float* Wlin = (const float*)d_in[9];
  const float* blin = (const float*)d_in[10];
  float* out = (float*)d_out;

  void* args[] = { (void*)&x, (void*)&Wi1, (void*)&Whh1, (void*)&Wih2, (void*)&Whh2,
                   (void*)&bih1, (void*)&bhh1, (void*)&bih2, (void*)&bhh2,
                   (void*)&Wlin, (void*)&blin, (void*)&out };
  hipLaunchCooperativeKernel((void*)rnn_kernel, dim3(GRID_WGS), dim3(BLOCK),
                             args, 0, stream);
}

// Round 14
// 3301.631 us; speedup vs baseline: 1.5478x; 1.2047x over previous
//
#include <hip/hip_runtime.h>

#define NB 256      // batch
#define NT 512      // time steps
#define NH 1024     // hidden
#define BH (NB * NH)
#define GRID_WGS 256
#define BLOCK 512
#define T2 (2 * NT)
#define FSTRIDE 32  // flags padded to one 128B line each

typedef __attribute__((ext_vector_type(8))) __bf16 bfrag;
typedef __attribute__((ext_vector_type(4))) float f32x4;
typedef __attribute__((ext_vector_type(4))) unsigned u32x4;
typedef __attribute__((ext_vector_type(8))) unsigned short u16x8;
typedef unsigned short us;

// h1(t) in buf[t&3]; h2(t) in buf[t&3] (quad buffers, skew-1-proof)
__device__ __attribute__((aligned(16))) us g_h1[4 * BH];
__device__ __attribute__((aligned(16))) us g_h2[4 * BH];
// per-(group,slot) monotonic flags, one 128B line EACH (padded against
// same-line store serialization); +NT+2 per launch, never reset -> replay safe
__device__ __attribute__((aligned(128))) unsigned g_flag[GRID_WGS * FSTRIDE];

__device__ __forceinline__ us f2bf(float f) {
  union { float f; unsigned u; } v; v.f = f;
  unsigned r = v.u + 0x7FFFu + ((v.u >> 16) & 1u);  // RTE
  return (us)(r >> 16);
}
__device__ __forceinline__ float bf2f(us u) {
  union { unsigned u; float f; } v; v.u = ((unsigned)u) << 16;
  return v.f;
}
__device__ __forceinline__ bfrag cvt8(const float* __restrict__ p) {
  f32x4 a = *reinterpret_cast<const f32x4*>(p);
  f32x4 b = *reinterpret_cast<const f32x4*>(p + 4);
  u16x8 u;
#pragma unroll
  for (int i = 0; i < 4; ++i) { u[i] = f2bf(a[i]); u[i + 4] = f2bf(b[i]); }
  union { u16x8 u; bfrag b; } c; c.u = u; return c.b;
}

// ---- device-coherent (sc0 sc1 -> L3 coherence point) ops
union f16u { u32x4 v; bfrag b; u16x8 s; };
__device__ __forceinline__ u32x4 ld16_dev(const void* p) {
  u32x4 r;
  asm volatile("global_load_dwordx4 %0, %1, off sc0 sc1" : "=v"(r) : "v"(p));
  return r;   // caller must s_waitcnt before use
}
__device__ __forceinline__ unsigned ld4_dev(const void* p) {
  unsigned r;
  asm volatile("global_load_dword %0, %1, off sc0 sc1\n\ts_waitcnt vmcnt(0)"
               : "=v"(r) : "v"(p) : "memory");
  return r;
}
__device__ __forceinline__ void st4_dev(void* p, unsigned v) {
  asm volatile("global_store_dword %0, %1, off sc0 sc1" :: "v"(p), "v"(v) : "memory");
}

// poll 4 padded flags (slots s0..s0+3) with lanes 0..3; no sleep (RT-dominated)
__device__ __forceinline__ void wait4(const unsigned* gf, int s0, int lane, unsigned tgt) {
  const unsigned* fp = gf + (s0 + (lane & 3)) * FSTRIDE;
  unsigned v = tgt;
  for (;;) {
    if (lane < 4) v = ld4_dev(fp);
    if (!__any((int)(v < tgt))) break;
  }
}
__device__ __forceinline__ void wait32(const unsigned* gf, int lane, unsigned tgt) {
  const unsigned* fp = gf + (lane & 31) * FSTRIDE;
  unsigned v = tgt;
  for (;;) {
    if (lane < 32) v = ld4_dev(fp);
    if (!__any((int)(v < tgt))) break;
  }
}

// out(t)[r_g, c=w] = dot(h2(t)[r_g,:], Wlin[w,:]) + blin[w]; waves 0,1
__device__ __forceinline__ void out_row(const us* h2, int r_g, int w, int lane,
                                        const float* __restrict__ Wlin,
                                        const float* __restrict__ blin,
                                        float* __restrict__ out, int t) {
  const us* hp = h2 + r_g * NH + lane * 16;
  const float* wl = Wlin + w * NH + lane * 16;
  f16u h0, h1v;
  h0.v  = ld16_dev(hp);
  h1v.v = ld16_dev(hp + 8);
  asm volatile("s_waitcnt vmcnt(0)" ::: "memory");
  __builtin_amdgcn_sched_barrier(0);
  float s = 0.f;
#pragma unroll
  for (int e = 0; e < 8; ++e) {
    s = fmaf(bf2f(h0.s[e]),  wl[e],     s);
    s = fmaf(bf2f(h1v.s[e]), wl[8 + e], s);
  }
#pragma unroll
  for (int m = 1; m < 64; m <<= 1) s += __shfl_xor(s, m);
  if (lane == 0) out[r_g * T2 + w * NT + t] = s + blin[w];
}

#define MFMA(a, b, c) __builtin_amdgcn_mfma_f32_16x16x32_bf16((a), (b), (c), 0, 0, 0)

__global__ void __launch_bounds__(BLOCK, 2) rnn_kernel(
    const float* __restrict__ x,     // [B][2][T]
    const float* __restrict__ Wi1,   // [H][2]
    const float* __restrict__ Whh1,  // [H][H]
    const float* __restrict__ Wih2,  // [H][H]
    const float* __restrict__ Whh2,  // [H][H]
    const float* __restrict__ bih1,
    const float* __restrict__ bhh1,
    const float* __restrict__ bih2,
    const float* __restrict__ bhh2,
    const float* __restrict__ Wlin,  // [2][H]
    const float* __restrict__ blin,  // [2]
    float* __restrict__ out)         // [B][2][T]
{
  const int bid = blockIdx.x, tid = threadIdx.x;
  const int w = tid >> 6, lane = tid & 63;
  const int mb = bid >> 5, nb = bid & 31;  // group rows [mb*32,+32); slot cols [nb*32,+32)
  unsigned* gf = g_flag + mb * 32 * FSTRIDE;
  const unsigned fb = ld4_dev(&gf[nb * FSTRIDE]);   // own flag -> stable base

  // zero t<0 tiles: h1(-1)=h1 buf3; h2(-2)=h2 buf2; h2(-1)=h2 buf3
  {
    const int zrow = tid >> 4, zc = tid & 15;
    const int off_d = ((mb * 32 + zrow) * NH + nb * 32) / 2 + zc;
    st4_dev((unsigned*)(g_h1 + 3 * BH) + off_d, 0u);
    st4_dev((unsigned*)(g_h2 + 2 * BH) + off_d, 0u);
    st4_dev((unsigned*)(g_h2 + 3 * BH) + off_d, 0u);
  }

  // ---- persistent weights: wave w owns K-slice [w*128,+128), 32 cols
  const int fr = lane & 15;
  const int ko = (lane >> 4) << 3;        // 0,8,16,24
  const int kbase = w * 128;
  bfrag w1[2][4], w2i[2][4], w2h[2][4];   // [col-half cf][k-step st]
#pragma unroll
  for (int cf = 0; cf < 2; ++cf)
#pragma unroll
    for (int st = 0; st < 4; ++st) {
      const int off = (nb * 32 + cf * 16 + fr) * NH + kbase + st * 32 + ko;
      w1[cf][st]  = cvt8(Whh1 + off);
      w2i[cf][st] = cvt8(Wih2 + off);
      w2h[cf][st] = cvt8(Whh2 + off);
    }

  // ---- per-thread epilogue constants (2 adjacent cols of one row)
  const int rl = tid >> 4, cl = (tid & 15) * 2;
  const int grow = mb * 32 + rl, gcol = nb * 32 + cl;
  const float b1s0 = bih1[gcol] + bhh1[gcol];
  const float b1s1 = bih1[gcol + 1] + bhh1[gcol + 1];
  const float b2s0 = bih2[gcol] + bhh2[gcol];
  const float b2s1 = bih2[gcol + 1] + bhh2[gcol + 1];
  const float wi00 = Wi1[gcol * 2],       wi01 = Wi1[gcol * 2 + 1];
  const float wi10 = Wi1[(gcol + 1) * 2], wi11 = Wi1[(gcol + 1) * 2 + 1];
  const float* xrow = x + grow * T2;

  __shared__ float redA[8][32][36];
  __shared__ float redB[8][32][36];

  const int arow0 = mb * 32 + fr;     // A-frag row base (+16 for mf1)
  const int prow = (lane >> 4) << 2;  // C/D row base within 16x16 frag
  const int r_g = bid;                // this WG's out row (mb*32+nb)

  // preamble complete -> publish fb+1
  asm volatile("s_waitcnt vmcnt(0)" ::: "memory");
  __syncthreads();
  if (tid == 0) st4_dev(&gf[nb * FSTRIDE], fb + 1u);

  for (int p = 0; p <= NT; ++p) {
    const us* h1_prev = g_h1 + ((p + 3) & 3) * BH;   // h1(p-1)
    us*       h1_cur  = g_h1 + (p & 3) * BH;         // h1(p)
    const us* h2_pp   = g_h2 + ((p + 2) & 3) * BH;   // h2(p-2)
    us*       h2_cur  = g_h2 + ((p + 3) & 3) * BH;   // h2(p-1)
    const us* h2_out  = g_h2 + ((p + 1) & 3) * BH;   // h2(p-3)

    const float x0 = xrow[p < NT ? p : 0], x1 = xrow[NT + (p < NT ? p : 0)];

    // wave w waits only on its 4 K-producer slots
    wait4(gf, w * 4, lane, fb + 1u + (unsigned)p);
    __builtin_amdgcn_sched_barrier(0);

    // issue all 16 fragment loads (a1: 8, a2: 8), counted-wait overlap
    f16u a1[2][4], a2[2][4];
#pragma unroll
    for (int mf = 0; mf < 2; ++mf) {
      const us* pa1 = h1_prev + (arow0 + mf * 16) * NH + kbase + ko;
      const us* pa2 = h2_pp   + (arow0 + mf * 16) * NH + kbase + ko;
#pragma unroll
      for (int st = 0; st < 4; ++st) {
        a1[mf][st].v = ld16_dev(pa1 + st * 32);
        a2[mf][st].v = ld16_dev(pa2 + st * 32);
      }
    }

    f32x4 accA[2][2] = {}; f32x4 accB[2][2] = {};
    asm volatile("s_waitcnt vmcnt(8)" ::: "memory");   // mf0's 8 loads done
    __builtin_amdgcn_sched_barrier(0);
#pragma unroll
    for (int st = 0; st < 4; ++st) {
      accA[0][0] = MFMA(a1[0][st].b, w1[0][st],  accA[0][0]);
      accA[0][1] = MFMA(a1[0][st].b, w1[1][st],  accA[0][1]);
      accB[0][0] = MFMA(a1[0][st].b, w2i[0][st], accB[0][0]);
      accB[0][1] = MFMA(a1[0][st].b, w2i[1][st], accB[0][1]);
      accB[0][0] = MFMA(a2[0][st].b, w2h[0][st], accB[0][0]);
      accB[0][1] = MFMA(a2[0][st].b, w2h[1][st], accB[0][1]);
    }
    asm volatile("s_waitcnt vmcnt(0)" ::: "memory");   // mf1's loads done
    __builtin_amdgcn_sched_barrier(0);
#pragma unroll
    for (int st = 0; st < 4; ++st) {
      accA[1][0] = MFMA(a1[1][st].b, w1[0][st],  accA[1][0]);
      accA[1][1] = MFMA(a1[1][st].b, w1[1][st],  accA[1][1]);
      accB[1][0] = MFMA(a1[1][st].b, w2i[0][st], accB[1][0]);
      accB[1][1] = MFMA(a1[1][st].b, w2i[1][st], accB[1][1]);
      accB[1][0] = MFMA(a2[1][st].b, w2h[0][st], accB[1][0]);
      accB[1][1] = MFMA(a2[1][st].b, w2h[1][st], accB[1][1]);
    }

    // k-partials to LDS  (C/D: col = lane&15, row = (lane>>4)*4 + r)
#pragma unroll
    for (int mf = 0; mf < 2; ++mf)
#pragma unroll
      for (int cf = 0; cf < 2; ++cf)
#pragma unroll
        for (int r = 0; r < 4; ++r) {
          redA[w][mf * 16 + prow + r][cf * 16 + fr] = accA[mf][cf][r];
          redB[w][mf * 16 + prow + r][cf * 16 + fr] = accB[mf][cf][r];
        }
    __syncthreads();

    // 8-way k-reduction + fused epilogue (2 adjacent cols per thread)
    float sA0 = 0.f, sA1 = 0.f, sB0 = 0.f, sB1 = 0.f;
#pragma unroll
    for (int u = 0; u < 8; ++u) {
      const float2 a = *reinterpret_cast<const float2*>(&redA[u][rl][cl]);
      const float2 b = *reinterpret_cast<const float2*>(&redB[u][rl][cl]);
      sA0 += a.x; sA1 += a.y; sB0 += b.x; sB1 += b.y;
    }
    if (p < NT) {
      const float v0 = sA0 + b1s0 + x0 * wi00 + x1 * wi01;
      const float v1 = sA1 + b1s1 + x0 * wi10 + x1 * wi11;
      st4_dev(h1_cur + grow * NH + gcol,
              (unsigned)f2bf(tanhf(v0)) | ((unsigned)f2bf(tanhf(v1)) << 16));
    }
    if (p >= 1) {
      const float v0 = sB0 + b2s0;
      const float v1 = sB1 + b2s1;
      st4_dev(h2_cur + grow * NH + gcol,
              (unsigned)f2bf(tanhf(v0)) | ((unsigned)f2bf(tanhf(v1)) << 16));
    }

    // release: coherent writes acked at L3, all waves done, then publish
    asm volatile("s_waitcnt vmcnt(0)" ::: "memory");
    __syncthreads();
    if (tid == 0) st4_dev(&gf[nb * FSTRIDE], fb + 2u + (unsigned)p);

    // out(p-3): OFF the publish path; buffer safe until my phase p+1 publish
    if (p >= 3 && w < 2)
      out_row(h2_out, r_g, w, lane, Wlin, blin, out, p - 3);
  }

  // tail: out(NT-2), out(NT-1) need all slots through phase NT
  wait32(gf, lane, fb + 2u + (unsigned)NT);
  if (w < 2) {
    out_row(g_h2 + ((NT - 2) & 3) * BH, r_g, w, lane, Wlin, blin, out, NT - 2);
    out_row(g_h2 + ((NT - 1) & 3) * BH, r_g, w, lane, Wlin, blin, out, NT - 1);
  }
}

extern "C" void kernel_launch(void* const* d_in, const int* in_sizes, int n_in,
                              void* d_out, int out_size, void* d_ws, size_t ws_size,
                              hipStream_t stream) {
  (void)in_sizes; (void)n_in; (void)d_ws; (void)ws_size; (void)out_size;
  const float* x    = (const float*)d_in[0];
  const float* Wi1  = (const float*)d_in[1];
  const float* Whh1 = (const float*)d_in[2];
  const float* bih1 = (const float*)d_in[3];
  const float* bhh1 = (const float*)d_in[4];
  const float* Wih2 = (const float*)d_in[5];
  const float* Whh2 = (const float*)d_in[6];
  const float* bih2 = (const float*)d_in[7];
  const float* bhh2 = (const float*)d_in[8];
  const float* Wlin = (const float*)d_in[9];
  const float* blin = (const float*)d_in[10];
  float* out = (float*)d_out;

  void* args[] = { (void*)&x, (void*)&Wi1, (void*)&Whh1, (void*)&Wih2, (void*)&Whh2,
                   (void*)&bih1, (void*)&bhh1, (void*)&bih2, (void*)&bhh2,
                   (void*)&Wlin, (void*)&blin, (void*)&out };
  hipLaunchCooperativeKernel((void*)rnn_kernel, dim3(GRID_WGS), dim3(BLOCK),
                             args, 0, stream);
}